// Round 3
// baseline (99.829 us; speedup 1.0000x reference)
//
#include <hip/hip_runtime.h>
#include <math.h>
#include <stdint.h>

#define BB 128
#define MM 50
#define CC 43
#define IMGF 416.0f

// block decomposition: scale0 52x52 (11 chunks/img), scale1 26x26 (3), scale2 13x13 (1)
#define NBLK0 1408
#define NBLK01 1792
#define NBLK_TOTAL 1920

#define CPI 3552          // padded cells per image (2704+676+169 = 3549 -> 3552)
#define SOFF1 2704
#define SOFF2 3380

// workspace layout (bytes)
#define GTM_BYTES (BB * CPI * 8)               // 3,637,248  u64 GT-incidence masks
#define PART_OFF  GTM_BYTES
#define PART_BYTES (NBLK_TOTAL * 4 * 4)        // 30,720
#define CNT_OFF   (PART_OFF + PART_BYTES)      // 3,667,968 (16B aligned)
#define WS_BYTES  (CNT_OFF + 16)               // 3,667,984
#define FILL_N16  (WS_BYTES / 16)              // 229,249 uint4 words

// bce = max(x,0) - x*t + log1p(e^-|x|), exact algebraic rewrite with fast intrinsics
__device__ __forceinline__ float bce_fast(float x, bool t) {
    float e = __expf(-fabsf(x));
    float l = __logf(1.0f + e);
    return fmaxf(x, 0.0f) - (t ? x : 0.0f) + l;
}

// focal: let x' = t?x:-x. bce = relu(-x') + log1p(e^-|x'|); 1-pt = x'>=0 ? e/(1+e) : 1/(1+e)
__device__ __forceinline__ float focal_fast(float x, bool t) {
    float xp = t ? x : -x;
    float e = __expf(-fabsf(xp));
    float d = 1.0f + e;
    float l = __logf(d);
    float bce = fmaxf(-xp, 0.0f) + l;
    float om = __builtin_amdgcn_rcpf(d);
    if (xp >= 0.0f) om *= e;      // om = 1 - pt
    return 0.25f * om * om * bce;
}

__global__ __launch_bounds__(256) void v3_fill(uint4* __restrict__ p, int n) {
    int i = blockIdx.x * 256 + threadIdx.x;
    if (i < n) p[i] = make_uint4(0u, 0u, 0u, 0u);
}

__global__ __launch_bounds__(256) void v3_main(
    const float* __restrict__ cls0, const float* __restrict__ reg0, const float* __restrict__ obj0,
    const float* __restrict__ cls1, const float* __restrict__ reg1, const float* __restrict__ obj1,
    const float* __restrict__ cls2, const float* __restrict__ reg2, const float* __restrict__ obj2,
    const float* __restrict__ bboxes, const int* __restrict__ labels,
    unsigned long long* __restrict__ gtm, float* __restrict__ partials,
    unsigned* __restrict__ counter, float* __restrict__ out)
{
    const int bid = blockIdx.x;
    int s, b, chunk;
    if (bid < NBLK0)       { s = 0; b = bid / 11; chunk = bid - 11 * b; }
    else if (bid < NBLK01) { int r = bid - NBLK0; s = 1; b = r / 3; chunk = r - 3 * b; }
    else                   { s = 2; b = bid - NBLK01; chunk = 0; }

    int W, A, soff; float strd, inv_strd;
    const float *cls, *reg, *obj;
    if (s == 0)      { W = 52; A = 2704; soff = 0;     strd = 8.f;  inv_strd = 0.125f;   cls = cls0; reg = reg0; obj = obj0; }
    else if (s == 1) { W = 26; A = 676;  soff = SOFF1; strd = 16.f; inv_strd = 0.0625f;  cls = cls1; reg = reg1; obj = obj1; }
    else             { W = 13; A = 169;  soff = SOFF2; strd = 32.f; inv_strd = 0.03125f; cls = cls2; reg = reg2; obj = obj2; }

    unsigned long long* __restrict__ g = gtm + (size_t)b * CPI + soff;
    const int tid = threadIdx.x;
    const int a_lo = chunk << 8;
    const int a_hi = min(a_lo + 255, A - 1);
    int ay_lo, ay_hi;
    if (s == 0)      { ay_lo = a_lo / 52; ay_hi = a_hi / 52; }
    else if (s == 1) { ay_lo = a_lo / 26; ay_hi = a_hi / 26; }
    else             { ay_lo = 0;         ay_hi = 12; }

    __shared__ int    s_lab[MM];
    __shared__ float4 s_boxv[MM];

    // ---- Phase 1: stage GTs + idempotent scatter of GT-incidence bits ----
    if (tid < MM) {
        int lab = labels[b * MM + tid];
        float4 bb = ((const float4*)bboxes)[b * MM + tid];
        float4 pb = make_float4(bb.x * IMGF, bb.y * IMGF, bb.z * IMGF, bb.w * IMGF);
        s_boxv[tid] = pb;
        s_lab[tid] = min(max(lab, 0), CC - 1);
        if (lab >= 0) {
            float cx = (pb.x + pb.z) * 0.5f;
            float cy = (pb.y + pb.w) * 0.5f;
            int gx = (int)(cx * inv_strd); gx = min(max(gx, 0), W - 1);
            int gy = (int)(cy * inv_strd); gy = min(max(gy, 0), W - 1);
            if (gy >= ay_lo - 1 && gy <= ay_hi + 1) {   // row-filter: only GTs touching this chunk
                unsigned long long bit = 1ull << tid;
                #pragma unroll
                for (int dy = -1; dy <= 1; ++dy) {
                    int yy = gy + dy;
                    if ((unsigned)yy < (unsigned)W) {
                        #pragma unroll
                        for (int dx = -1; dx <= 1; ++dx) {
                            int xx = gx + dx;
                            if ((unsigned)xx < (unsigned)W)
                                atomicOr(&g[yy * W + xx], bit);
                        }
                    }
                }
            }
        }
    }
    __syncthreads();   // drains vmcnt: our own atomics complete before our reads

    // ---- Phase 2: per-anchor obj + box; collect fg info ----
    const int a = a_lo + tid;
    const bool active = (a < A);
    int ay;
    if (s == 0) ay = a / 52; else if (s == 1) ay = a / 26; else ay = a / 13;
    const int ax = a - ay * W;

    float obj_t = 0.f, cls_t = 0.f, box_t = 0.f, nfg = 0.f;
    unsigned long long gm = 0ull;
    if (active) gm = g[a];
    const bool fg = (gm != 0ull);
    if (active) {
        float xo = obj[(size_t)b * A + a];
        obj_t = bce_fast(xo, fg);
    }
    unsigned lo = 0u, hi = 0u;
    if (fg) {
        nfg = 1.0f;
        // multi-hot class mask = union of labels over covering GTs
        unsigned long long t = gm;
        while (t) {
            int m = (int)__builtin_ctzll(t);
            t &= t - 1;
            int lc = s_lab[m];
            if (lc < 32) lo |= 1u << lc; else hi |= 1u << (lc - 32);
        }
        // last-write-wins box target = max set bit
        int mstar = 63 - (int)__builtin_clzll(gm);
        float4 tb = s_boxv[mstar];
        const float* rp = reg + (size_t)b * 4 * A + a;
        float rx = rp[0], ry = rp[(size_t)A], rw = rp[(size_t)2 * A], rh = rp[(size_t)3 * A];
        float px = ((float)ax + rx) * strd;
        float py = ((float)ay + ry) * strd;
        rw = fminf(fmaxf(rw, -10.0f), 10.0f);
        rh = fminf(fmaxf(rh, -10.0f), 10.0f);
        float pw = __expf(rw) * strd;
        float ph = __expf(rh) * strd;
        float p0 = px - pw * 0.5f, p1 = py - ph * 0.5f;
        float p2 = px + pw * 0.5f, p3 = py + ph * 0.5f;
        float ix1 = fmaxf(p0, tb.x), iy1 = fmaxf(p1, tb.y);
        float ix2 = fminf(p2, tb.z), iy2 = fminf(p3, tb.w);
        float inter = fmaxf(ix2 - ix1, 0.0f) * fmaxf(iy2 - iy1, 0.0f);
        float pa = (p2 - p0) * (p3 - p1);
        float ta = (tb.z - tb.x) * (tb.w - tb.y);
        float iou = inter * __builtin_amdgcn_rcpf(pa + ta - inter + 1e-7f);
        box_t = 1.0f - iou;
    }

    // ---- Phase 3: deterministic block-local compaction of fg anchors ----
    __shared__ unsigned long long s_pack[256];
    __shared__ int s_wcnt[4];
    const int lane = tid & 63, wid = tid >> 6;
    unsigned long long ball = __ballot(fg);
    int pre = __popcll(ball & ((1ull << lane) - 1ull));
    if (lane == 0) s_wcnt[wid] = __popcll(ball);
    __syncthreads();
    int off = 0;
    #pragma unroll
    for (int w = 0; w < 4; ++w) off += (w < wid) ? s_wcnt[w] : 0;
    const int fgN = s_wcnt[0] + s_wcnt[1] + s_wcnt[2] + s_wcnt[3];
    if (fg) s_pack[off + pre] = ((unsigned long long)a << 43) |
                                ((unsigned long long)hi << 32) | (unsigned long long)lo;
    __syncthreads();

    // ---- Phase 4: cooperative focal over fgN*43 items, all lanes busy ----
    const float* __restrict__ cbase = cls + (size_t)b * CC * A;
    float acc = 0.f;
    const int total = fgN * CC;
    for (int i = tid; i < total; i += 256) {
        int j = i / CC;            // compile-time magic div
        int c = i - j * CC;
        unsigned long long w = s_pack[j];
        int aj = (int)(w >> 43);
        unsigned hj = (unsigned)(w >> 32) & 0x7FFu;
        unsigned lj = (unsigned)w;
        float xv = cbase[(size_t)c * A + aj];
        bool bit = (c < 32) ? ((lj >> c) & 1u) : ((hj >> (c - 32)) & 1u);
        acc += focal_fast(xv, bit);
    }
    cls_t = acc;

    // ---- Phase 5: block reduction ----
    float v0 = obj_t, v1 = cls_t, v2 = box_t, v3 = nfg;
    for (int o = 32; o > 0; o >>= 1) {
        v0 += __shfl_xor(v0, o);
        v1 += __shfl_xor(v1, o);
        v2 += __shfl_xor(v2, o);
        v3 += __shfl_xor(v3, o);
    }
    __shared__ float s_red[4][4];
    if (lane == 0) { s_red[wid][0] = v0; s_red[wid][1] = v1; s_red[wid][2] = v2; s_red[wid][3] = v3; }
    __syncthreads();

    __shared__ int s_lastf;
    if (tid == 0) {
        float o = 0.f, c = 0.f, bx = 0.f, nf = 0.f;
        for (int w = 0; w < 4; ++w) {
            o += s_red[w][0]; c += s_red[w][1]; bx += s_red[w][2]; nf += s_red[w][3];
        }
        float* p = partials + (size_t)bid * 4;
        __hip_atomic_store(&p[0], o,  __ATOMIC_RELAXED, __HIP_MEMORY_SCOPE_AGENT);
        __hip_atomic_store(&p[1], c,  __ATOMIC_RELAXED, __HIP_MEMORY_SCOPE_AGENT);
        __hip_atomic_store(&p[2], bx, __ATOMIC_RELAXED, __HIP_MEMORY_SCOPE_AGENT);
        __hip_atomic_store(&p[3], nf, __ATOMIC_RELAXED, __HIP_MEMORY_SCOPE_AGENT);
        unsigned old = __hip_atomic_fetch_add(counter, 1u, __ATOMIC_ACQ_REL, __HIP_MEMORY_SCOPE_AGENT);
        s_lastf = (old == NBLK_TOTAL - 1) ? 1 : 0;
    }
    __syncthreads();

    // ---- Phase 6: last block performs the final reduction ----
    if (s_lastf) {
        double o[3] = {0,0,0}, c[3] = {0,0,0}, bx[3] = {0,0,0}, nf[3] = {0,0,0};
        for (int i = tid; i < NBLK_TOTAL; i += 256) {
            int sc = (i < NBLK0) ? 0 : ((i < NBLK01) ? 1 : 2);
            float* p = partials + (size_t)i * 4;
            o[sc]  += (double)__hip_atomic_load(&p[0], __ATOMIC_RELAXED, __HIP_MEMORY_SCOPE_AGENT);
            c[sc]  += (double)__hip_atomic_load(&p[1], __ATOMIC_RELAXED, __HIP_MEMORY_SCOPE_AGENT);
            bx[sc] += (double)__hip_atomic_load(&p[2], __ATOMIC_RELAXED, __HIP_MEMORY_SCOPE_AGENT);
            nf[sc] += (double)__hip_atomic_load(&p[3], __ATOMIC_RELAXED, __HIP_MEMORY_SCOPE_AGENT);
        }
        for (int ofs = 32; ofs > 0; ofs >>= 1) {
            #pragma unroll
            for (int sc = 0; sc < 3; ++sc) {
                o[sc]  += __shfl_xor(o[sc],  ofs);
                c[sc]  += __shfl_xor(c[sc],  ofs);
                bx[sc] += __shfl_xor(bx[sc], ofs);
                nf[sc] += __shfl_xor(nf[sc], ofs);
            }
        }
        __shared__ double s_dred[4][12];
        if (lane == 0) {
            #pragma unroll
            for (int sc = 0; sc < 3; ++sc) {
                s_dred[wid][sc*4+0] = o[sc];  s_dred[wid][sc*4+1] = c[sc];
                s_dred[wid][sc*4+2] = bx[sc]; s_dred[wid][sc*4+3] = nf[sc];
            }
        }
        __syncthreads();
        if (tid == 0) {
            double total = 0.0;
            #pragma unroll
            for (int sc = 0; sc < 3; ++sc) {
                double os = 0, cs = 0, bs = 0, ns = 0;
                for (int w = 0; w < 4; ++w) {
                    os += s_dred[w][sc*4+0]; cs += s_dred[w][sc*4+1];
                    bs += s_dred[w][sc*4+2]; ns += s_dred[w][sc*4+3];
                }
                double n = (ns > 1.0) ? ns : 1.0;
                total += 0.5 * (cs / (n * (double)CC)) + 7.5 * (bs / n) + 1.0 * (os / n);
            }
            out[0] = (float)(total / 3.0);
        }
    }
}

extern "C" void kernel_launch(void* const* d_in, const int* in_sizes, int n_in,
                              void* d_out, int out_size, void* d_ws, size_t ws_size,
                              hipStream_t stream) {
    const float* cls0 = (const float*)d_in[0];
    const float* reg0 = (const float*)d_in[1];
    const float* obj0 = (const float*)d_in[2];
    const float* cls1 = (const float*)d_in[3];
    const float* reg1 = (const float*)d_in[4];
    const float* obj1 = (const float*)d_in[5];
    const float* cls2 = (const float*)d_in[6];
    const float* reg2 = (const float*)d_in[7];
    const float* obj2 = (const float*)d_in[8];
    const float* bboxes = (const float*)d_in[9];
    const int*   labels = (const int*)d_in[10];

    unsigned long long* gtm = (unsigned long long*)d_ws;
    float*    partials = (float*)((char*)d_ws + PART_OFF);
    unsigned* counter  = (unsigned*)((char*)d_ws + CNT_OFF);

    v3_fill<<<(FILL_N16 + 255) / 256, 256, 0, stream>>>((uint4*)d_ws, FILL_N16);
    v3_main<<<NBLK_TOTAL, 256, 0, stream>>>(cls0, reg0, obj0, cls1, reg1, obj1,
                                            cls2, reg2, obj2, bboxes, labels,
                                            gtm, partials, counter, (float*)d_out);
}

// Round 4
// 80.259 us; speedup vs baseline: 1.2438x; 1.2438x over previous
//
#include <hip/hip_runtime.h>
#include <math.h>
#include <stdint.h>

#define BB 128
#define MM 50
#define CC 43
#define IMGF 416.0f

// block decomposition: scale0 52x52 (11 chunks/img), scale1 26x26 (3), scale2 13x13 (1)
#define NBLK0 1408
#define NBLK01 1792
#define NBLK_TOTAL 1920

// workspace: partials[1920*4] floats, then counter (16B-aligned)
#define PART_BYTES (NBLK_TOTAL * 4 * 4)
#define CNT_OFF PART_BYTES

// bce = max(x,0) - x*t + log1p(e^-|x|), exact algebraic rewrite with fast intrinsics
__device__ __forceinline__ float bce_fast(float x, bool t) {
    float e = __expf(-fabsf(x));
    float l = __logf(1.0f + e);
    return fmaxf(x, 0.0f) - (t ? x : 0.0f) + l;
}

// focal: let x' = t?x:-x. bce = relu(-x') + log1p(e^-|x'|); 1-pt = x'>=0 ? e/(1+e) : 1/(1+e)
__device__ __forceinline__ float focal_fast(float x, bool t) {
    float xp = t ? x : -x;
    float e = __expf(-fabsf(xp));
    float d = 1.0f + e;
    float l = __logf(d);
    float bce = fmaxf(-xp, 0.0f) + l;
    float om = __builtin_amdgcn_rcpf(d);
    if (xp >= 0.0f) om *= e;      // om = 1 - pt
    return 0.25f * om * om * bce;
}

__global__ __launch_bounds__(256) void v3_main(
    const float* __restrict__ cls0, const float* __restrict__ reg0, const float* __restrict__ obj0,
    const float* __restrict__ cls1, const float* __restrict__ reg1, const float* __restrict__ obj1,
    const float* __restrict__ cls2, const float* __restrict__ reg2, const float* __restrict__ obj2,
    const float* __restrict__ bboxes, const int* __restrict__ labels,
    float* __restrict__ partials, unsigned* __restrict__ counter, float* __restrict__ out)
{
    const int bid = blockIdx.x;
    int s, b, chunk;
    if (bid < NBLK0)       { s = 0; b = bid / 11; chunk = bid - 11 * b; }
    else if (bid < NBLK01) { int r = bid - NBLK0; s = 1; b = r / 3; chunk = r - 3 * b; }
    else                   { s = 2; b = bid - NBLK01; chunk = 0; }

    int W, A; float strd, inv_strd;
    const float *cls, *reg, *obj;
    if (s == 0)      { W = 52; A = 2704; strd = 8.f;  inv_strd = 0.125f;   cls = cls0; reg = reg0; obj = obj0; }
    else if (s == 1) { W = 26; A = 676;  strd = 16.f; inv_strd = 0.0625f;  cls = cls1; reg = reg1; obj = obj1; }
    else             { W = 13; A = 169;  strd = 32.f; inv_strd = 0.03125f; cls = cls2; reg = reg2; obj = obj2; }

    const int tid = threadIdx.x;
    const int lane = tid & 63, wid = tid >> 6;
    const int a_lo = chunk << 8;
    const int a_hi = min(a_lo + 255, A - 1);

    // ---- LDS state: GT staging + per-cell GT-incidence masks (block-local) ----
    __shared__ int    s_lab[MM];
    __shared__ float4 s_boxv[MM];
    __shared__ unsigned s_glo[256], s_ghi[256];   // GT-index bitmask per cell (m<32 / m>=32)
    __shared__ unsigned long long s_pack[256];
    __shared__ int s_wcnt[4];

    // Phase 1a: zero cell masks; 50 lanes stage GT data + compute centers
    s_glo[tid] = 0u; s_ghi[tid] = 0u;
    int gx = -1, gy = -1, my_lab = -1;
    if (tid < MM) {
        my_lab = labels[b * MM + tid];
        float4 bb = ((const float4*)bboxes)[b * MM + tid];
        float4 pb = make_float4(bb.x * IMGF, bb.y * IMGF, bb.z * IMGF, bb.w * IMGF);
        s_boxv[tid] = pb;
        s_lab[tid] = min(max(my_lab, 0), CC - 1);
        float cx = (pb.x + pb.z) * 0.5f;
        float cy = (pb.y + pb.w) * 0.5f;
        gx = (int)(cx * inv_strd); gx = min(max(gx, 0), W - 1);
        gy = (int)(cy * inv_strd); gy = min(max(gy, 0), W - 1);
    }
    __syncthreads();

    // Phase 1b: idempotent scatter of GT bits into this block's cell window
    if (tid < MM && my_lab >= 0) {
        unsigned bit = 1u << (tid & 31);
        bool is_hi = (tid >= 32);
        #pragma unroll
        for (int dy = -1; dy <= 1; ++dy) {
            int yy = gy + dy;
            if ((unsigned)yy < (unsigned)W) {
                #pragma unroll
                for (int dx = -1; dx <= 1; ++dx) {
                    int xx = gx + dx;
                    if ((unsigned)xx < (unsigned)W) {
                        int ac = yy * W + xx;
                        if (ac >= a_lo && ac <= a_hi) {
                            if (is_hi) atomicOr(&s_ghi[ac - a_lo], bit);
                            else       atomicOr(&s_glo[ac - a_lo], bit);
                        }
                    }
                }
            }
        }
    }
    __syncthreads();

    // ---- Phase 2: per-anchor obj + box ----
    const int a = a_lo + tid;
    const bool active = (a < A);
    int ay;
    if (s == 0) ay = a / 52; else if (s == 1) ay = a / 26; else ay = a / 13;
    const int ax = a - ay * W;

    unsigned glo = s_glo[tid], ghi = s_ghi[tid];
    const bool fg = (glo | ghi) != 0u;   // inactive cells never receive bits

    float obj_t = 0.f, box_t = 0.f, nfg = 0.f;
    if (active) {
        float xo = obj[(size_t)b * A + a];
        obj_t = bce_fast(xo, fg);
    }
    unsigned lo = 0u, hi = 0u;
    if (fg) {
        nfg = 1.0f;
        // class multi-hot = union of labels over covering GTs
        unsigned t = glo;
        while (t) {
            int m = __builtin_ctz(t); t &= t - 1;
            int lc = s_lab[m];
            if (lc < 32) lo |= 1u << lc; else hi |= 1u << (lc - 32);
        }
        t = ghi;
        while (t) {
            int m = 32 + __builtin_ctz(t); t &= t - 1;
            int lc = s_lab[m];
            if (lc < 32) lo |= 1u << lc; else hi |= 1u << (lc - 32);
        }
        // last-write-wins box target = max set GT index
        int mstar = ghi ? (32 + 31 - __builtin_clz(ghi)) : (31 - __builtin_clz(glo));
        float4 tb = s_boxv[mstar];
        const float* rp = reg + (size_t)b * 4 * A + a;
        float rx = rp[0], ry = rp[(size_t)A], rw = rp[(size_t)2 * A], rh = rp[(size_t)3 * A];
        float px = ((float)ax + rx) * strd;
        float py = ((float)ay + ry) * strd;
        rw = fminf(fmaxf(rw, -10.0f), 10.0f);
        rh = fminf(fmaxf(rh, -10.0f), 10.0f);
        float pw = __expf(rw) * strd;
        float ph = __expf(rh) * strd;
        float p0 = px - pw * 0.5f, p1 = py - ph * 0.5f;
        float p2 = px + pw * 0.5f, p3 = py + ph * 0.5f;
        float ix1 = fmaxf(p0, tb.x), iy1 = fmaxf(p1, tb.y);
        float ix2 = fminf(p2, tb.z), iy2 = fminf(p3, tb.w);
        float inter = fmaxf(ix2 - ix1, 0.0f) * fmaxf(iy2 - iy1, 0.0f);
        float pa = (p2 - p0) * (p3 - p1);
        float ta = (tb.z - tb.x) * (tb.w - tb.y);
        float iou = inter * __builtin_amdgcn_rcpf(pa + ta - inter + 1e-7f);
        box_t = 1.0f - iou;
    }

    // ---- Phase 3: deterministic block-local compaction of fg anchors ----
    unsigned long long ball = __ballot(fg);
    int pre = __popcll(ball & ((1ull << lane) - 1ull));
    if (lane == 0) s_wcnt[wid] = __popcll(ball);
    __syncthreads();
    int off = 0;
    #pragma unroll
    for (int w = 0; w < 4; ++w) off += (w < wid) ? s_wcnt[w] : 0;
    const int fgN = s_wcnt[0] + s_wcnt[1] + s_wcnt[2] + s_wcnt[3];
    if (fg) s_pack[off + pre] = ((unsigned long long)a << 43) |
                                ((unsigned long long)hi << 32) | (unsigned long long)lo;
    __syncthreads();

    // ---- Phase 4: focal. Wave w owns channels c = w, w+4, ... (wave-uniform c);
    //      lanes stride the compacted fg anchors -> coalesced within the 1KB window.
    const float* __restrict__ cbase = cls + (size_t)b * CC * A;
    float cls_t = 0.f;
    for (int c = wid; c < CC; c += 4) {
        const float* __restrict__ ch = cbase + (size_t)c * A;
        for (int j = lane; j < fgN; j += 64) {
            unsigned long long w = s_pack[j];
            int aj = (int)(w >> 43);
            unsigned hj = (unsigned)(w >> 32) & 0x7FFu;
            unsigned lj = (unsigned)w;
            bool bit = (c < 32) ? ((lj >> c) & 1u) : ((hj >> (c - 32)) & 1u);
            cls_t += focal_fast(ch[aj], bit);
        }
    }

    // ---- Phase 5: block reduction ----
    float v0 = obj_t, v1 = cls_t, v2 = box_t, v3 = nfg;
    for (int o = 32; o > 0; o >>= 1) {
        v0 += __shfl_xor(v0, o);
        v1 += __shfl_xor(v1, o);
        v2 += __shfl_xor(v2, o);
        v3 += __shfl_xor(v3, o);
    }
    __shared__ float s_red[4][4];
    if (lane == 0) { s_red[wid][0] = v0; s_red[wid][1] = v1; s_red[wid][2] = v2; s_red[wid][3] = v3; }
    __syncthreads();

    __shared__ int s_lastf;
    if (tid == 0) {
        float o = 0.f, c = 0.f, bx = 0.f, nf = 0.f;
        for (int w = 0; w < 4; ++w) {
            o += s_red[w][0]; c += s_red[w][1]; bx += s_red[w][2]; nf += s_red[w][3];
        }
        float* p = partials + (size_t)bid * 4;
        __hip_atomic_store(&p[0], o,  __ATOMIC_RELAXED, __HIP_MEMORY_SCOPE_AGENT);
        __hip_atomic_store(&p[1], c,  __ATOMIC_RELAXED, __HIP_MEMORY_SCOPE_AGENT);
        __hip_atomic_store(&p[2], bx, __ATOMIC_RELAXED, __HIP_MEMORY_SCOPE_AGENT);
        __hip_atomic_store(&p[3], nf, __ATOMIC_RELAXED, __HIP_MEMORY_SCOPE_AGENT);
        unsigned old = __hip_atomic_fetch_add(counter, 1u, __ATOMIC_ACQ_REL, __HIP_MEMORY_SCOPE_AGENT);
        s_lastf = (old == NBLK_TOTAL - 1) ? 1 : 0;
    }
    __syncthreads();

    // ---- Phase 6: last block performs the final reduction ----
    if (s_lastf) {
        double o[3] = {0,0,0}, c[3] = {0,0,0}, bx[3] = {0,0,0}, nf[3] = {0,0,0};
        for (int i = tid; i < NBLK_TOTAL; i += 256) {
            int sc = (i < NBLK0) ? 0 : ((i < NBLK01) ? 1 : 2);
            float* p = partials + (size_t)i * 4;
            o[sc]  += (double)__hip_atomic_load(&p[0], __ATOMIC_RELAXED, __HIP_MEMORY_SCOPE_AGENT);
            c[sc]  += (double)__hip_atomic_load(&p[1], __ATOMIC_RELAXED, __HIP_MEMORY_SCOPE_AGENT);
            bx[sc] += (double)__hip_atomic_load(&p[2], __ATOMIC_RELAXED, __HIP_MEMORY_SCOPE_AGENT);
            nf[sc] += (double)__hip_atomic_load(&p[3], __ATOMIC_RELAXED, __HIP_MEMORY_SCOPE_AGENT);
        }
        for (int ofs = 32; ofs > 0; ofs >>= 1) {
            #pragma unroll
            for (int sc = 0; sc < 3; ++sc) {
                o[sc]  += __shfl_xor(o[sc],  ofs);
                c[sc]  += __shfl_xor(c[sc],  ofs);
                bx[sc] += __shfl_xor(bx[sc], ofs);
                nf[sc] += __shfl_xor(nf[sc], ofs);
            }
        }
        __shared__ double s_dred[4][12];
        if (lane == 0) {
            #pragma unroll
            for (int sc = 0; sc < 3; ++sc) {
                s_dred[wid][sc*4+0] = o[sc];  s_dred[wid][sc*4+1] = c[sc];
                s_dred[wid][sc*4+2] = bx[sc]; s_dred[wid][sc*4+3] = nf[sc];
            }
        }
        __syncthreads();
        if (tid == 0) {
            double total = 0.0;
            #pragma unroll
            for (int sc = 0; sc < 3; ++sc) {
                double os = 0, cs = 0, bs = 0, ns = 0;
                for (int w = 0; w < 4; ++w) {
                    os += s_dred[w][sc*4+0]; cs += s_dred[w][sc*4+1];
                    bs += s_dred[w][sc*4+2]; ns += s_dred[w][sc*4+3];
                }
                double n = (ns > 1.0) ? ns : 1.0;
                total += 0.5 * (cs / (n * (double)CC)) + 7.5 * (bs / n) + 1.0 * (os / n);
            }
            out[0] = (float)(total / 3.0);
        }
    }
}

extern "C" void kernel_launch(void* const* d_in, const int* in_sizes, int n_in,
                              void* d_out, int out_size, void* d_ws, size_t ws_size,
                              hipStream_t stream) {
    const float* cls0 = (const float*)d_in[0];
    const float* reg0 = (const float*)d_in[1];
    const float* obj0 = (const float*)d_in[2];
    const float* cls1 = (const float*)d_in[3];
    const float* reg1 = (const float*)d_in[4];
    const float* obj1 = (const float*)d_in[5];
    const float* cls2 = (const float*)d_in[6];
    const float* reg2 = (const float*)d_in[7];
    const float* obj2 = (const float*)d_in[8];
    const float* bboxes = (const float*)d_in[9];
    const int*   labels = (const int*)d_in[10];

    float*    partials = (float*)d_ws;
    unsigned* counter  = (unsigned*)((char*)d_ws + CNT_OFF);

    hipMemsetAsync(counter, 0, sizeof(unsigned), stream);
    v3_main<<<NBLK_TOTAL, 256, 0, stream>>>(cls0, reg0, obj0, cls1, reg1, obj1,
                                            cls2, reg2, obj2, bboxes, labels,
                                            partials, counter, (float*)d_out);
}

// Round 5
// 76.032 us; speedup vs baseline: 1.3130x; 1.0556x over previous
//
#include <hip/hip_runtime.h>
#include <math.h>
#include <stdint.h>

#define BB 128
#define MM 50
#define CC 43
#define IMGF 416.0f

// block decomposition: scale0 52x52 (11 chunks/img), scale1 26x26 (3), scale2 13x13 (1)
#define NBLK0 1408
#define NBLK01 1792
#define NBLK_TOTAL 1920

// workspace: partials[1920*4] floats, then counter (16B-aligned)
#define PART_BYTES (NBLK_TOTAL * 4 * 4)
#define CNT_OFF PART_BYTES

// bce = max(x,0) - x*t + log1p(e^-|x|), exact algebraic rewrite with fast intrinsics
__device__ __forceinline__ float bce_fast(float x, bool t) {
    float e = __expf(-fabsf(x));
    float l = __logf(1.0f + e);
    return fmaxf(x, 0.0f) - (t ? x : 0.0f) + l;
}

// focal: let x' = t?x:-x. bce = relu(-x') + log1p(e^-|x'|); 1-pt = x'>=0 ? e/(1+e) : 1/(1+e)
__device__ __forceinline__ float focal_fast(float x, bool t) {
    float xp = t ? x : -x;
    float e = __expf(-fabsf(xp));
    float d = 1.0f + e;
    float l = __logf(d);
    float bce = fmaxf(-xp, 0.0f) + l;
    float om = __builtin_amdgcn_rcpf(d);
    if (xp >= 0.0f) om *= e;      // om = 1 - pt
    return 0.25f * om * om * bce;
}

__global__ __launch_bounds__(256) void v3_main(
    const float* __restrict__ cls0, const float* __restrict__ reg0, const float* __restrict__ obj0,
    const float* __restrict__ cls1, const float* __restrict__ reg1, const float* __restrict__ obj1,
    const float* __restrict__ cls2, const float* __restrict__ reg2, const float* __restrict__ obj2,
    const float* __restrict__ bboxes, const int* __restrict__ labels,
    float* __restrict__ partials, unsigned* __restrict__ counter, float* __restrict__ out)
{
    const int bid = blockIdx.x;
    int s, b, chunk;
    if (bid < NBLK0)       { s = 0; b = bid / 11; chunk = bid - 11 * b; }
    else if (bid < NBLK01) { int r = bid - NBLK0; s = 1; b = r / 3; chunk = r - 3 * b; }
    else                   { s = 2; b = bid - NBLK01; chunk = 0; }

    int W, A; float strd, inv_strd;
    const float *cls, *reg, *obj;
    if (s == 0)      { W = 52; A = 2704; strd = 8.f;  inv_strd = 0.125f;   cls = cls0; reg = reg0; obj = obj0; }
    else if (s == 1) { W = 26; A = 676;  strd = 16.f; inv_strd = 0.0625f;  cls = cls1; reg = reg1; obj = obj1; }
    else             { W = 13; A = 169;  strd = 32.f; inv_strd = 0.03125f; cls = cls2; reg = reg2; obj = obj2; }

    const int tid = threadIdx.x;
    const int lane = tid & 63, wid = tid >> 6;
    const int a_lo = chunk << 8;
    const int a_hi = min(a_lo + 255, A - 1);

    // ---- LDS state: GT staging + per-cell GT-incidence masks (block-local) ----
    __shared__ int    s_lab[MM];
    __shared__ float4 s_boxv[MM];
    __shared__ unsigned s_glo[256], s_ghi[256];   // GT-index bitmask per cell (m<32 / m>=32)
    __shared__ unsigned long long s_pack[256];
    __shared__ int s_wcnt[4];

    // Phase 1a: zero cell masks; 50 lanes stage GT data + compute centers
    s_glo[tid] = 0u; s_ghi[tid] = 0u;
    int gx = -1, gy = -1, my_lab = -1;
    if (tid < MM) {
        my_lab = labels[b * MM + tid];
        float4 bb = ((const float4*)bboxes)[b * MM + tid];
        float4 pb = make_float4(bb.x * IMGF, bb.y * IMGF, bb.z * IMGF, bb.w * IMGF);
        s_boxv[tid] = pb;
        s_lab[tid] = min(max(my_lab, 0), CC - 1);
        float cx = (pb.x + pb.z) * 0.5f;
        float cy = (pb.y + pb.w) * 0.5f;
        gx = (int)(cx * inv_strd); gx = min(max(gx, 0), W - 1);
        gy = (int)(cy * inv_strd); gy = min(max(gy, 0), W - 1);
    }
    __syncthreads();

    // Phase 1b: idempotent scatter of GT bits into this block's cell window
    if (tid < MM && my_lab >= 0) {
        unsigned bit = 1u << (tid & 31);
        bool is_hi = (tid >= 32);
        #pragma unroll
        for (int dy = -1; dy <= 1; ++dy) {
            int yy = gy + dy;
            if ((unsigned)yy < (unsigned)W) {
                #pragma unroll
                for (int dx = -1; dx <= 1; ++dx) {
                    int xx = gx + dx;
                    if ((unsigned)xx < (unsigned)W) {
                        int ac = yy * W + xx;
                        if (ac >= a_lo && ac <= a_hi) {
                            if (is_hi) atomicOr(&s_ghi[ac - a_lo], bit);
                            else       atomicOr(&s_glo[ac - a_lo], bit);
                        }
                    }
                }
            }
        }
    }
    __syncthreads();

    // ---- Phase 2: per-anchor obj + box ----
    const int a = a_lo + tid;
    const bool active = (a < A);
    int ay;
    if (s == 0) ay = a / 52; else if (s == 1) ay = a / 26; else ay = a / 13;
    const int ax = a - ay * W;

    unsigned glo = s_glo[tid], ghi = s_ghi[tid];
    const bool fg = (glo | ghi) != 0u;   // inactive cells never receive bits

    float obj_t = 0.f, box_t = 0.f, nfg = 0.f;
    if (active) {
        float xo = obj[(size_t)b * A + a];
        obj_t = bce_fast(xo, fg);
    }
    unsigned lo = 0u, hi = 0u;
    if (fg) {
        nfg = 1.0f;
        // class multi-hot = union of labels over covering GTs
        unsigned t = glo;
        while (t) {
            int m = __builtin_ctz(t); t &= t - 1;
            int lc = s_lab[m];
            if (lc < 32) lo |= 1u << lc; else hi |= 1u << (lc - 32);
        }
        t = ghi;
        while (t) {
            int m = 32 + __builtin_ctz(t); t &= t - 1;
            int lc = s_lab[m];
            if (lc < 32) lo |= 1u << lc; else hi |= 1u << (lc - 32);
        }
        // last-write-wins box target = max set GT index
        int mstar = ghi ? (32 + 31 - __builtin_clz(ghi)) : (31 - __builtin_clz(glo));
        float4 tb = s_boxv[mstar];
        const float* rp = reg + (size_t)b * 4 * A + a;
        float rx = rp[0], ry = rp[(size_t)A], rw = rp[(size_t)2 * A], rh = rp[(size_t)3 * A];
        float px = ((float)ax + rx) * strd;
        float py = ((float)ay + ry) * strd;
        rw = fminf(fmaxf(rw, -10.0f), 10.0f);
        rh = fminf(fmaxf(rh, -10.0f), 10.0f);
        float pw = __expf(rw) * strd;
        float ph = __expf(rh) * strd;
        float p0 = px - pw * 0.5f, p1 = py - ph * 0.5f;
        float p2 = px + pw * 0.5f, p3 = py + ph * 0.5f;
        float ix1 = fmaxf(p0, tb.x), iy1 = fmaxf(p1, tb.y);
        float ix2 = fminf(p2, tb.z), iy2 = fminf(p3, tb.w);
        float inter = fmaxf(ix2 - ix1, 0.0f) * fmaxf(iy2 - iy1, 0.0f);
        float pa = (p2 - p0) * (p3 - p1);
        float ta = (tb.z - tb.x) * (tb.w - tb.y);
        float iou = inter * __builtin_amdgcn_rcpf(pa + ta - inter + 1e-7f);
        box_t = 1.0f - iou;
    }

    // ---- Phase 3: deterministic block-local compaction of fg anchors ----
    unsigned long long ball = __ballot(fg);
    int pre = __popcll(ball & ((1ull << lane) - 1ull));
    if (lane == 0) s_wcnt[wid] = __popcll(ball);
    __syncthreads();
    int off = 0;
    #pragma unroll
    for (int w = 0; w < 4; ++w) off += (w < wid) ? s_wcnt[w] : 0;
    const int fgN = s_wcnt[0] + s_wcnt[1] + s_wcnt[2] + s_wcnt[3];
    if (fg) s_pack[off + pre] = ((unsigned long long)a << 43) |
                                ((unsigned long long)hi << 32) | (unsigned long long)lo;
    __syncthreads();

    // ---- Phase 4: focal. Thread t owns compacted fg anchor t; the 43-channel
    //      loop is compile-time unrolled -> 43 independent gathers in flight
    //      (this MLP is what made R2 fast; R4's runtime-bound loops lost it).
    float cls_t = 0.f;
    if (tid < fgN) {
        unsigned long long w = s_pack[tid];
        int aj = (int)(w >> 43);
        unsigned hj = (unsigned)(w >> 32) & 0x7FFu;
        unsigned lj = (unsigned)w;
        const float* __restrict__ p = cls + (size_t)b * CC * A + aj;
        float acc = 0.f;
        #pragma unroll
        for (int c = 0; c < CC; ++c) {
            float xv = p[(size_t)c * A];
            bool bit = (c < 32) ? ((lj >> c) & 1u) : ((hj >> (c - 32)) & 1u);
            acc += focal_fast(xv, bit);
        }
        cls_t = acc;
    }

    // ---- Phase 5: block reduction ----
    float v0 = obj_t, v1 = cls_t, v2 = box_t, v3 = nfg;
    for (int o = 32; o > 0; o >>= 1) {
        v0 += __shfl_xor(v0, o);
        v1 += __shfl_xor(v1, o);
        v2 += __shfl_xor(v2, o);
        v3 += __shfl_xor(v3, o);
    }
    __shared__ float s_red[4][4];
    if (lane == 0) { s_red[wid][0] = v0; s_red[wid][1] = v1; s_red[wid][2] = v2; s_red[wid][3] = v3; }
    __syncthreads();

    __shared__ int s_lastf;
    if (tid == 0) {
        float o = 0.f, c = 0.f, bx = 0.f, nf = 0.f;
        for (int w = 0; w < 4; ++w) {
            o += s_red[w][0]; c += s_red[w][1]; bx += s_red[w][2]; nf += s_red[w][3];
        }
        float* p = partials + (size_t)bid * 4;
        __hip_atomic_store(&p[0], o,  __ATOMIC_RELAXED, __HIP_MEMORY_SCOPE_AGENT);
        __hip_atomic_store(&p[1], c,  __ATOMIC_RELAXED, __HIP_MEMORY_SCOPE_AGENT);
        __hip_atomic_store(&p[2], bx, __ATOMIC_RELAXED, __HIP_MEMORY_SCOPE_AGENT);
        __hip_atomic_store(&p[3], nf, __ATOMIC_RELAXED, __HIP_MEMORY_SCOPE_AGENT);
        unsigned old = __hip_atomic_fetch_add(counter, 1u, __ATOMIC_ACQ_REL, __HIP_MEMORY_SCOPE_AGENT);
        s_lastf = (old == NBLK_TOTAL - 1) ? 1 : 0;
    }
    __syncthreads();

    // ---- Phase 6: last block performs the final reduction ----
    if (s_lastf) {
        double o[3] = {0,0,0}, c[3] = {0,0,0}, bx[3] = {0,0,0}, nf[3] = {0,0,0};
        for (int i = tid; i < NBLK_TOTAL; i += 256) {
            int sc = (i < NBLK0) ? 0 : ((i < NBLK01) ? 1 : 2);
            float* p = partials + (size_t)i * 4;
            o[sc]  += (double)__hip_atomic_load(&p[0], __ATOMIC_RELAXED, __HIP_MEMORY_SCOPE_AGENT);
            c[sc]  += (double)__hip_atomic_load(&p[1], __ATOMIC_RELAXED, __HIP_MEMORY_SCOPE_AGENT);
            bx[sc] += (double)__hip_atomic_load(&p[2], __ATOMIC_RELAXED, __HIP_MEMORY_SCOPE_AGENT);
            nf[sc] += (double)__hip_atomic_load(&p[3], __ATOMIC_RELAXED, __HIP_MEMORY_SCOPE_AGENT);
        }
        for (int ofs = 32; ofs > 0; ofs >>= 1) {
            #pragma unroll
            for (int sc = 0; sc < 3; ++sc) {
                o[sc]  += __shfl_xor(o[sc],  ofs);
                c[sc]  += __shfl_xor(c[sc],  ofs);
                bx[sc] += __shfl_xor(bx[sc], ofs);
                nf[sc] += __shfl_xor(nf[sc], ofs);
            }
        }
        __shared__ double s_dred[4][12];
        if (lane == 0) {
            #pragma unroll
            for (int sc = 0; sc < 3; ++sc) {
                s_dred[wid][sc*4+0] = o[sc];  s_dred[wid][sc*4+1] = c[sc];
                s_dred[wid][sc*4+2] = bx[sc]; s_dred[wid][sc*4+3] = nf[sc];
            }
        }
        __syncthreads();
        if (tid == 0) {
            double total = 0.0;
            #pragma unroll
            for (int sc = 0; sc < 3; ++sc) {
                double os = 0, cs = 0, bs = 0, ns = 0;
                for (int w = 0; w < 4; ++w) {
                    os += s_dred[w][sc*4+0]; cs += s_dred[w][sc*4+1];
                    bs += s_dred[w][sc*4+2]; ns += s_dred[w][sc*4+3];
                }
                double n = (ns > 1.0) ? ns : 1.0;
                total += 0.5 * (cs / (n * (double)CC)) + 7.5 * (bs / n) + 1.0 * (os / n);
            }
            out[0] = (float)(total / 3.0);
        }
    }
}

extern "C" void kernel_launch(void* const* d_in, const int* in_sizes, int n_in,
                              void* d_out, int out_size, void* d_ws, size_t ws_size,
                              hipStream_t stream) {
    const float* cls0 = (const float*)d_in[0];
    const float* reg0 = (const float*)d_in[1];
    const float* obj0 = (const float*)d_in[2];
    const float* cls1 = (const float*)d_in[3];
    const float* reg1 = (const float*)d_in[4];
    const float* obj1 = (const float*)d_in[5];
    const float* cls2 = (const float*)d_in[6];
    const float* reg2 = (const float*)d_in[7];
    const float* obj2 = (const float*)d_in[8];
    const float* bboxes = (const float*)d_in[9];
    const int*   labels = (const int*)d_in[10];

    float*    partials = (float*)d_ws;
    unsigned* counter  = (unsigned*)((char*)d_ws + CNT_OFF);

    hipMemsetAsync(counter, 0, sizeof(unsigned), stream);
    v3_main<<<NBLK_TOTAL, 256, 0, stream>>>(cls0, reg0, obj0, cls1, reg1, obj1,
                                            cls2, reg2, obj2, bboxes, labels,
                                            partials, counter, (float*)d_out);
}